// Round 1
// baseline (1923.279 us; speedup 1.0000x reference)
//
#include <hip/hip_runtime.h>
#include <math.h>

#define NNODES 100000
#define NEDGES 1200000

// fp32 constants, matching the numpy reference's evaluation order/precision
#define C_EC   1.602176634e-19f
#define C_E2   (C_EC * C_EC)                     // folded in fp32
#define C_4PI  12.566370614359172f               // np.float32(4*pi)
#define C_EPS0 8.8541878128e-12f
#define C_A    (C_4PI * C_EPS0)                  // fp32 fold of 4*pi*eps0
#define C_B    1e-10f

__device__ __forceinline__ float softplus_f(float x) {
    // stable log1p(exp(x)) == logaddexp(x, 0)
    return fmaxf(x, 0.0f) + log1pf(expf(-fabsf(x)));
}
__device__ __forceinline__ float mish_f(float x) {
    return x * tanhf(softplus_f(x));
}

// one 64-wide GEMM layer over a 64-row LDS tile (stride 65 to dodge bank conflicts)
// thread computes rows r0..r0+3, cols c0..c0+3. wsm is [k][j] (transposed) in LDS.
__device__ __forceinline__ void gemm64(const float* xs, const float* wsm,
                                       const float* bsv, int r0, int c0,
                                       float acc[4][4])
{
    #pragma unroll
    for (int i = 0; i < 4; ++i)
        #pragma unroll
        for (int j = 0; j < 4; ++j) acc[i][j] = bsv[c0 + j];
    #pragma unroll 8
    for (int k = 0; k < 64; ++k) {
        float4 wv = *(const float4*)&wsm[(k << 6) + c0];   // b128, 2-way free
        #pragma unroll
        for (int i = 0; i < 4; ++i) {
            float xv = xs[(r0 + i) * 65 + k];              // b32 broadcast, pad-65
            acc[i][0] = fmaf(xv, wv.x, acc[i][0]);
            acc[i][1] = fmaf(xv, wv.y, acc[i][1]);
            acc[i][2] = fmaf(xv, wv.z, acc[i][2]);
            acc[i][3] = fmaf(xv, wv.w, acc[i][3]);
        }
    }
}

// K0: transpose the 8 weight matrices once: wt[m][k*64+j] = w_m[j*64+k]
__global__ __launch_bounds__(256) void transpose_w_kernel(
    const float* __restrict__ w0, const float* __restrict__ w1,
    const float* __restrict__ w2, const float* __restrict__ w3,
    const float* __restrict__ w4, const float* __restrict__ w5,
    const float* __restrict__ w6, const float* __restrict__ w7,
    float* __restrict__ wt)
{
    int g = blockIdx.x * 256 + threadIdx.x;      // 0..32767
    int m = g >> 12;
    int e = g & 4095;
    const float* w;
    switch (m) {
        case 0: w = w0; break; case 1: w = w1; break;
        case 2: w = w2; break; case 3: w = w3; break;
        case 4: w = w4; break; case 5: w = w5; break;
        case 6: w = w6; break; default: w = w7; break;
    }
    int j = e >> 6, k = e & 63;
    wt[(m << 12) + (k << 6) + j] = w[e];
}

// K1/K2: out = mish-MLP(x) for nrows rows. wt1/wt2 already transposed ([k][j]).
__global__ __launch_bounds__(256) void mlp64_kernel(
    const float* __restrict__ x,
    const float* __restrict__ wt1, const float* __restrict__ b1,
    const float* __restrict__ wt2, const float* __restrict__ b2,
    float* __restrict__ out, int nrows)
{
    __shared__ __align__(16) float xs[64 * 65];
    __shared__ __align__(16) float w1s[4096];
    __shared__ __align__(16) float w2s[4096];
    __shared__ float b1s[64], b2s[64];

    const int t = threadIdx.x;
    const int row0 = blockIdx.x << 6;
    const int r0 = (t >> 4) << 2;
    const int c0 = (t & 15) << 2;

    // weights: straight float4 copy (already in LDS layout)
    {
        const float4* s1 = (const float4*)wt1;
        const float4* s2 = (const float4*)wt2;
        float4* d1 = (float4*)w1s;
        float4* d2 = (float4*)w2s;
        #pragma unroll
        for (int i = 0; i < 4; ++i) {
            int v = i * 256 + t;
            d1[v] = s1[v];
            d2[v] = s2[v];
        }
        if (t < 64) { b1s[t] = b1[t]; b2s[t] = b2[t]; }
    }
    // x tile
    #pragma unroll
    for (int i = 0; i < 4; ++i) {
        int v = i * 256 + t;
        int r = v >> 4;
        int kq = (v & 15) << 2;
        int row = row0 + r;
        float4 xv = make_float4(0.f, 0.f, 0.f, 0.f);
        if (row < nrows) xv = *(const float4*)(x + ((size_t)row << 6) + kq);
        float* dp = &xs[r * 65 + kq];
        dp[0] = xv.x; dp[1] = xv.y; dp[2] = xv.z; dp[3] = xv.w;
    }
    __syncthreads();

    float acc[4][4];
    gemm64(xs, w1s, b1s, r0, c0, acc);           // layer 1
    __syncthreads();                             // xs reads done
    #pragma unroll
    for (int i = 0; i < 4; ++i)
        #pragma unroll
        for (int j = 0; j < 4; ++j)
            xs[(r0 + i) * 65 + c0 + j] = mish_f(acc[i][j]);
    __syncthreads();
    gemm64(xs, w2s, b2s, r0, c0, acc);           // layer 2 (linear)

    #pragma unroll
    for (int i = 0; i < 4; ++i) {
        int row = row0 + r0 + i;
        if (row < nrows) {
            float4 o = make_float4(acc[i][0], acc[i][1], acc[i][2], acc[i][3]);
            *(float4*)(out + ((size_t)row << 6) + c0) = o;
        }
    }
}

// K3: fused per-edge pipeline: we-MLP(edge_feats) -> Coulomb with gathered hs/hd
//     -> wm-MLP -> atomic scatter into hacc (d_out). NEDGES % 64 == 0.
__global__ __launch_bounds__(256) void edge_kernel(
    const float* __restrict__ efeat,
    const float* __restrict__ hs, const float* __restrict__ hd,
    const int* __restrict__ src, const int* __restrict__ dst,
    const float* __restrict__ wt,
    const float* __restrict__ bwe1, const float* __restrict__ bwe2,
    const float* __restrict__ bwm1, const float* __restrict__ bwm2,
    float* __restrict__ hacc)
{
    __shared__ __align__(16) float xs[64 * 65];
    __shared__ __align__(16) float w1s[4096];
    __shared__ __align__(16) float w2s[4096];
    __shared__ float b1s[64], b2s[64];
    __shared__ int srcs[64], dsts[64];

    const int t = threadIdx.x;
    const int row0 = blockIdx.x << 6;
    const int r0 = (t >> 4) << 2;
    const int c0 = (t & 15) << 2;

    // we weights + indices + edge-feat tile
    {
        const float4* s1 = (const float4*)(wt + 4 * 4096);   // we_w1^T
        const float4* s2 = (const float4*)(wt + 5 * 4096);   // we_w2^T
        float4* d1 = (float4*)w1s;
        float4* d2 = (float4*)w2s;
        #pragma unroll
        for (int i = 0; i < 4; ++i) {
            int v = i * 256 + t;
            d1[v] = s1[v];
            d2[v] = s2[v];
        }
        if (t < 64) {
            b1s[t] = bwe1[t]; b2s[t] = bwe2[t];
            srcs[t] = src[row0 + t]; dsts[t] = dst[row0 + t];
        }
    }
    #pragma unroll
    for (int i = 0; i < 4; ++i) {
        int v = i * 256 + t;
        int r = v >> 4;
        int kq = (v & 15) << 2;
        float4 xv = *(const float4*)(efeat + ((size_t)(row0 + r) << 6) + kq);
        float* dp = &xs[r * 65 + kq];
        dp[0] = xv.x; dp[1] = xv.y; dp[2] = xv.z; dp[3] = xv.w;
    }
    __syncthreads();

    float acc[4][4];
    gemm64(xs, w1s, b1s, r0, c0, acc);           // we layer 1
    __syncthreads();
    #pragma unroll
    for (int i = 0; i < 4; ++i)
        #pragma unroll
        for (int j = 0; j < 4; ++j)
            xs[(r0 + i) * 65 + c0 + j] = mish_f(acc[i][j]);
    __syncthreads();
    float ef4[4][4];
    gemm64(xs, w2s, b2s, r0, c0, ef4);           // we layer 2 -> ef values
    __syncthreads();                             // all xs/w/b reads done

    // Coulomb elementwise with gathers; write h_nodes tile into xs.
    // exact np order: num=(hs*hd)*e^2 ; den=((4pi*eps0)*ef)*1e-10 ; h=num/den
    #pragma unroll
    for (int i = 0; i < 4; ++i) {
        int r = r0 + i;
        int s = srcs[r], d = dsts[r];
        float4 a = *(const float4*)(hs + ((size_t)s << 6) + c0);
        float4 b = *(const float4*)(hd + ((size_t)d << 6) + c0);
        float* dp = &xs[r * 65 + c0];
        dp[0] = ((a.x * b.x) * C_E2) / ((C_A * ef4[i][0]) * C_B);
        dp[1] = ((a.y * b.y) * C_E2) / ((C_A * ef4[i][1]) * C_B);
        dp[2] = ((a.z * b.z) * C_E2) / ((C_A * ef4[i][2]) * C_B);
        dp[3] = ((a.w * b.w) * C_E2) / ((C_A * ef4[i][3]) * C_B);
    }
    // swap in wm weights (safe: barrier above retired all we reads)
    {
        const float4* s1 = (const float4*)(wt + 6 * 4096);   // wm_w1^T
        const float4* s2 = (const float4*)(wt + 7 * 4096);   // wm_w2^T
        float4* d1 = (float4*)w1s;
        float4* d2 = (float4*)w2s;
        #pragma unroll
        for (int i = 0; i < 4; ++i) {
            int v = i * 256 + t;
            d1[v] = s1[v];
            d2[v] = s2[v];
        }
        if (t < 64) { b1s[t] = bwm1[t]; b2s[t] = bwm2[t]; }
    }
    __syncthreads();

    gemm64(xs, w1s, b1s, r0, c0, acc);           // wm layer 1
    __syncthreads();
    #pragma unroll
    for (int i = 0; i < 4; ++i)
        #pragma unroll
        for (int j = 0; j < 4; ++j)
            xs[(r0 + i) * 65 + c0 + j] = mish_f(acc[i][j]);
    __syncthreads();
    gemm64(xs, w2s, b2s, r0, c0, acc);           // wm layer 2 -> messages

    // scatter-sum into destination nodes
    #pragma unroll
    for (int i = 0; i < 4; ++i) {
        int d = dsts[r0 + i];
        float* p = hacc + ((size_t)d << 6) + c0;
        atomicAdd(p + 0, acc[i][0]);
        atomicAdd(p + 1, acc[i][1]);
        atomicAdd(p + 2, acc[i][2]);
        atomicAdd(p + 3, acc[i][3]);
    }
}

// K4: out = softplus(node_feats + out), in place, float4 over 1.6M vec4s
__global__ __launch_bounds__(256) void finalize_kernel(
    const float* __restrict__ nf, float* __restrict__ out)
{
    int g = blockIdx.x * 256 + threadIdx.x;
    float4 a = ((const float4*)nf)[g];
    float4 h = ((float4*)out)[g];
    float4 o;
    o.x = softplus_f(a.x + h.x);
    o.y = softplus_f(a.y + h.y);
    o.z = softplus_f(a.z + h.z);
    o.w = softplus_f(a.w + h.w);
    ((float4*)out)[g] = o;
}

extern "C" void kernel_launch(void* const* d_in, const int* in_sizes, int n_in,
                              void* d_out, int out_size, void* d_ws, size_t ws_size,
                              hipStream_t stream)
{
    const float* node_feats = (const float*)d_in[0];
    const float* edge_feats = (const float*)d_in[1];
    const int*   src        = (const int*)d_in[2];
    const int*   dst        = (const int*)d_in[3];
    const float* ws_w1 = (const float*)d_in[4];
    const float* ws_b1 = (const float*)d_in[5];
    const float* ws_w2 = (const float*)d_in[6];
    const float* ws_b2 = (const float*)d_in[7];
    const float* wd_w1 = (const float*)d_in[8];
    const float* wd_b1 = (const float*)d_in[9];
    const float* wd_w2 = (const float*)d_in[10];
    const float* wd_b2 = (const float*)d_in[11];
    const float* we_w1 = (const float*)d_in[12];
    const float* we_b1 = (const float*)d_in[13];
    const float* we_w2 = (const float*)d_in[14];
    const float* we_b2 = (const float*)d_in[15];
    const float* wm_w1 = (const float*)d_in[16];
    const float* wm_b1 = (const float*)d_in[17];
    const float* wm_w2 = (const float*)d_in[18];
    const float* wm_b2 = (const float*)d_in[19];

    // workspace layout: wt (8*4096 f) | hs (6.4M f) | hd (6.4M f)  ~= 51.7 MB
    float* wt = (float*)d_ws;
    float* hs = wt + 8 * 4096;
    float* hd = hs + (size_t)NNODES * 64;
    float* hacc = (float*)d_out;

    transpose_w_kernel<<<128, 256, 0, stream>>>(
        ws_w1, ws_w2, wd_w1, wd_w2, we_w1, we_w2, wm_w1, wm_w2, wt);

    const int node_tiles = (NNODES + 63) / 64;   // 1563
    mlp64_kernel<<<node_tiles, 256, 0, stream>>>(
        node_feats, wt + 0 * 4096, ws_b1, wt + 1 * 4096, ws_b2, hs, NNODES);
    mlp64_kernel<<<node_tiles, 256, 0, stream>>>(
        node_feats, wt + 2 * 4096, wd_b1, wt + 3 * 4096, wd_b2, hd, NNODES);

    hipMemsetAsync(d_out, 0, (size_t)out_size * sizeof(float), stream);

    edge_kernel<<<NEDGES / 64, 256, 0, stream>>>(
        edge_feats, hs, hd, src, dst, wt, we_b1, we_b2, wm_b1, wm_b2, hacc);

    finalize_kernel<<<(NNODES * 64) / (256 * 4), 256, 0, stream>>>(
        node_feats, (float*)d_out);
}

// Round 4
// 840.684 us; speedup vs baseline: 2.2878x; 2.2878x over previous
//
#include <hip/hip_runtime.h>
#include <math.h>

#define NNODES 100000
#define NEDGES 1200000

// fp32 constants, matching the numpy reference's evaluation order/precision
#define C_EC   1.602176634e-19f
#define C_E2   (C_EC * C_EC)                     // fp32 fold, ~2.57e-38 (normal)
#define C_4PI  12.566370614359172f               // np.float32(4*pi)
#define C_EPS0 8.8541878128e-12f
#define C_A    (C_4PI * C_EPS0)
#define C_B    1e-10f

typedef __attribute__((ext_vector_type(8))) short bf16x8;   // 8 bf16 = 4 VGPR
typedef __attribute__((ext_vector_type(4))) float f32x4;    // MFMA C/D

__device__ __forceinline__ unsigned short f2bf(float f) {
    unsigned u = __float_as_uint(f);
    u += 0x7fffu + ((u >> 16) & 1u);             // RNE
    return (unsigned short)(u >> 16);
}
__device__ __forceinline__ float bf2f(unsigned short s) {
    return __uint_as_float(((unsigned)s) << 16);
}
__device__ __forceinline__ float softplus_f(float x) {
    return fmaxf(x, 0.0f) + log1pf(__expf(-fabsf(x)));
}
// mish(x) = x*tanh(softplus(x)) = x*(u^2-1)/(u^2+1), u=1+e^x  -> one transcendental
__device__ __forceinline__ float mish_f(float x) {
    float e = __expf(fminf(x, 30.0f));           // clamp: mish(x>30)==x in fp32
    float n = e * e + 2.0f * e;
    return x * n / (n + 2.0f);
}

// ---- one 64->64 linear layer via MFMA, for one wave's 16 rows ----
// xs:  wave's LDS slice, 16 rows x 72 bf16 (stride 72: 144B rows keep b128 aligned)
// wg:  global bf16 weights, nn.Linear row-major W[n][k] (B-frag contiguous)
// acc[t] covers output cols t*16..t*16+15 (C/D: col=lane&15, row=(lane>>4)*4+reg)
// CALLER must ensure a barrier between the LDS writes that filled xs and this call.
__device__ __forceinline__ void mfma_layer(const unsigned short* xs,
                                           const unsigned short* __restrict__ wg,
                                           const float* __restrict__ bias,
                                           int lane, f32x4 acc[4])
{
    const int l15 = lane & 15, q = lane >> 4;
    bf16x8 a0 = *(const bf16x8*)(xs + l15 * 72 + q * 8);        // A[m=l15][k=q*8+j]
    bf16x8 a1 = *(const bf16x8*)(xs + l15 * 72 + 32 + q * 8);   // k in [32,64)
    #pragma unroll
    for (int t = 0; t < 4; ++t) {
        float bv = bias[t * 16 + l15];           // y = x@W.T + b : bias by col
        acc[t] = (f32x4){bv, bv, bv, bv};
        // B[k][n]=W[n][k]; lane holds k=q*8+j of row n=t*16+l15 -> 16B loads
        bf16x8 b0 = *(const bf16x8*)(wg + (t * 16 + l15) * 64 + q * 8);
        bf16x8 b1 = *(const bf16x8*)(wg + (t * 16 + l15) * 64 + 32 + q * 8);
        acc[t] = __builtin_amdgcn_mfma_f32_16x16x32_bf16(a0, b0, acc[t], 0, 0, 0);
        acc[t] = __builtin_amdgcn_mfma_f32_16x16x32_bf16(a1, b1, acc[t], 0, 0, 0);
    }
}

// mish(acc) -> bf16 into wave's LDS slice (A-layout rows for the next layer)
__device__ __forceinline__ void mish_to_lds(const f32x4 acc[4], unsigned short* hid, int lane)
{
    const int l15 = lane & 15, q = lane >> 4;
    #pragma unroll
    for (int t = 0; t < 4; ++t)
        #pragma unroll
        for (int j = 0; j < 4; ++j)
            hid[(q * 4 + j) * 72 + t * 16 + l15] = f2bf(mish_f(acc[t][j]));
}

// K0: convert the 8 weight matrices fp32 -> bf16, keep row-major
__global__ __launch_bounds__(256) void convert_w_kernel(
    const float* __restrict__ w0, const float* __restrict__ w1,
    const float* __restrict__ w2, const float* __restrict__ w3,
    const float* __restrict__ w4, const float* __restrict__ w5,
    const float* __restrict__ w6, const float* __restrict__ w7,
    unsigned short* __restrict__ wbf)
{
    int g = blockIdx.x * 256 + threadIdx.x;      // 8192 threads x 4 elems
    int m = g >> 10;
    int e = (g & 1023) * 4;
    const float* w;
    switch (m) {
        case 0: w = w0; break; case 1: w = w1; break;
        case 2: w = w2; break; case 3: w = w3; break;
        case 4: w = w4; break; case 5: w = w5; break;
        case 6: w = w6; break; default: w = w7; break;
    }
    float4 v = *(const float4*)(w + e);
    unsigned short* dp = wbf + m * 4096 + e;
    dp[0] = f2bf(v.x); dp[1] = f2bf(v.y); dp[2] = f2bf(v.z); dp[3] = f2bf(v.w);
}

// K1: fused ws+wd node MLPs -> hs, hd (bf16). 64 nodes/block, wave-owned 16-row
// slices; barriers guard every cross-lane LDS write->read handoff.
__global__ __launch_bounds__(256) void node_mlp_kernel(
    const float* __restrict__ x,
    const unsigned short* __restrict__ wbf,
    const float* __restrict__ bs1, const float* __restrict__ bs2,
    const float* __restrict__ bd1, const float* __restrict__ bd2,
    unsigned short* __restrict__ hs, unsigned short* __restrict__ hd)
{
    __shared__ __align__(16) unsigned short xs[64 * 72];
    __shared__ __align__(16) unsigned short hid[64 * 72];
    const int t = threadIdx.x, lane = t & 63, wave = t >> 6;
    const int row0 = blockIdx.x * 64 + wave * 16;
    unsigned short* xw = xs + wave * 16 * 72;
    unsigned short* hw = hid + wave * 16 * 72;
    const int l15 = lane & 15, q = lane >> 4;

    // stage 16 rows fp32 -> bf16 (zero-pad past NNODES)
    {
        int r = lane >> 2, c4 = lane & 3;
        #pragma unroll
        for (int i = 0; i < 4; ++i) {
            int col = (c4 + i * 4) * 4;
            float4 v = make_float4(0.f, 0.f, 0.f, 0.f);
            if (row0 + r < NNODES) v = *(const float4*)(x + (size_t)(row0 + r) * 64 + col);
            unsigned short* dp = xw + r * 72 + col;
            dp[0] = f2bf(v.x); dp[1] = f2bf(v.y); dp[2] = f2bf(v.z); dp[3] = f2bf(v.w);
        }
    }
    __syncthreads();                                   // xs staged -> readable

    f32x4 acc[4];
    // ws net
    mfma_layer(xw, wbf + 0 * 4096, bs1, lane, acc);
    mish_to_lds(acc, hw, lane);
    __syncthreads();                                   // hid written -> readable
    mfma_layer(hw, wbf + 1 * 4096, bs2, lane, acc);
    #pragma unroll
    for (int j = 0; j < 4; ++j) {
        int row = row0 + q * 4 + j;
        if (row < NNODES)
            #pragma unroll
            for (int t4 = 0; t4 < 4; ++t4)
                hs[(size_t)row * 64 + t4 * 16 + l15] = f2bf(acc[t4][j]);
    }
    // wd net (xs tile untouched; hid about to be overwritten -> WAR barrier)
    mfma_layer(xw, wbf + 2 * 4096, bd1, lane, acc);
    __syncthreads();                                   // retire hid reads (WAR)
    mish_to_lds(acc, hw, lane);
    __syncthreads();                                   // hid written -> readable
    mfma_layer(hw, wbf + 3 * 4096, bd2, lane, acc);
    #pragma unroll
    for (int j = 0; j < 4; ++j) {
        int row = row0 + q * 4 + j;
        if (row < NNODES)
            #pragma unroll
            for (int t4 = 0; t4 < 4; ++t4)
                hd[(size_t)row * 64 + t4 * 16 + l15] = f2bf(acc[t4][j]);
    }
}

// K2: fused edge pipeline, 64 edges/block, wave-owned rows, barrier-guarded.
__global__ __launch_bounds__(256) void edge_kernel(
    const float* __restrict__ efeat,
    const unsigned short* __restrict__ hs, const unsigned short* __restrict__ hd,
    const int* __restrict__ src, const int* __restrict__ dst,
    const unsigned short* __restrict__ wbf,
    const float* __restrict__ be1, const float* __restrict__ be2,
    const float* __restrict__ bm1, const float* __restrict__ bm2,
    float* __restrict__ out)
{
    __shared__ __align__(16) unsigned short xs[64 * 72];
    __shared__ __align__(16) unsigned short hid[64 * 72];
    const int t = threadIdx.x, lane = t & 63, wave = t >> 6;
    const int e0 = blockIdx.x * 64 + wave * 16;
    unsigned short* xw = xs + wave * 16 * 72;
    unsigned short* hw = hid + wave * 16 * 72;
    const int l15 = lane & 15, q = lane >> 4;

    // stage 16 edges' feats fp32 -> bf16
    {
        int r = lane >> 2, c4 = lane & 3;
        #pragma unroll
        for (int i = 0; i < 4; ++i) {
            int col = (c4 + i * 4) * 4;
            float4 v = *(const float4*)(efeat + (size_t)(e0 + r) * 64 + col);
            unsigned short* dp = xw + r * 72 + col;
            dp[0] = f2bf(v.x); dp[1] = f2bf(v.y); dp[2] = f2bf(v.z); dp[3] = f2bf(v.w);
        }
    }
    int sj[4], dj[4];
    #pragma unroll
    for (int j = 0; j < 4; ++j) {                // this lane's 4 edge rows
        sj[j] = src[e0 + q * 4 + j];
        dj[j] = dst[e0 + q * 4 + j];
    }
    __syncthreads();                                   // xs staged

    f32x4 acc[4], ef[4];
    mfma_layer(xw, wbf + 4 * 4096, be1, lane, acc);    // we layer 1
    mish_to_lds(acc, hw, lane);
    __syncthreads();                                   // hid written
    mfma_layer(hw, wbf + 5 * 4096, be2, lane, ef);     // we layer 2 -> ef (regs)
    __syncthreads();                                   // retire xs/hid reads (WAR)

    // Coulomb: gather hs[src], hd[dst] (bf16), exact np op order, h_nodes -> xw.
    // SINGULARITY GUARD: den=(C_A*ef)*C_B underflows to exactly 0 for |ef|<~1.3e-35
    // (our bf16-path ef can cancel to ~0 where np's fp32 ef doesn't) -> h would be
    // +-inf -> bf16 inf -> inf-inf=NaN inside wm MFMA. np's h there is ~<=1e-15
    // (since |ef_np - ef_ours| ~ 1e-2), so h=0 matches the reference to ~1e-15.
    #pragma unroll
    for (int j = 0; j < 4; ++j)
        #pragma unroll
        for (int t4 = 0; t4 < 4; ++t4) {
            int col = t4 * 16 + l15;
            float a = bf2f(hs[(size_t)sj[j] * 64 + col]);
            float b = bf2f(hd[(size_t)dj[j] * 64 + col]);
            float den = (C_A * ef[t4][j]) * C_B;
            float h = (den != 0.0f) ? ((a * b) * C_E2) / den : 0.0f;
            h = fminf(fmaxf(h, -1e30f), 1e30f);        // bf16-safe (no inf ever)
            xw[(q * 4 + j) * 72 + col] = f2bf(h);
        }
    __syncthreads();                                   // xs (h_nodes) written

    mfma_layer(xw, wbf + 6 * 4096, bm1, lane, acc);    // wm layer 1
    mish_to_lds(acc, hw, lane);
    __syncthreads();                                   // hid written
    mfma_layer(hw, wbf + 7 * 4096, bm2, lane, acc);    // wm layer 2 -> messages

    // scatter-sum: per (t4,j) the 16 lanes hit one node's contiguous 64B
    #pragma unroll
    for (int j = 0; j < 4; ++j) {
        float* p = out + (size_t)dj[j] * 64;
        #pragma unroll
        for (int t4 = 0; t4 < 4; ++t4)
            atomicAdd(p + t4 * 16 + l15, acc[t4][j]);
    }
}

// K3: out = softplus(node_feats + out), float4
__global__ __launch_bounds__(256) void finalize_kernel(
    const float* __restrict__ nf, float* __restrict__ out)
{
    int g = blockIdx.x * 256 + threadIdx.x;
    float4 a = ((const float4*)nf)[g];
    float4 h = ((float4*)out)[g];
    float4 o;
    o.x = softplus_f(a.x + h.x);
    o.y = softplus_f(a.y + h.y);
    o.z = softplus_f(a.z + h.z);
    o.w = softplus_f(a.w + h.w);
    ((float4*)out)[g] = o;
}

extern "C" void kernel_launch(void* const* d_in, const int* in_sizes, int n_in,
                              void* d_out, int out_size, void* d_ws, size_t ws_size,
                              hipStream_t stream)
{
    const float* node_feats = (const float*)d_in[0];
    const float* edge_feats = (const float*)d_in[1];
    const int*   src        = (const int*)d_in[2];
    const int*   dst        = (const int*)d_in[3];
    const float* ws_w1 = (const float*)d_in[4];
    const float* ws_b1 = (const float*)d_in[5];
    const float* ws_w2 = (const float*)d_in[6];
    const float* ws_b2 = (const float*)d_in[7];
    const float* wd_w1 = (const float*)d_in[8];
    const float* wd_b1 = (const float*)d_in[9];
    const float* wd_w2 = (const float*)d_in[10];
    const float* wd_b2 = (const float*)d_in[11];
    const float* we_w1 = (const float*)d_in[12];
    const float* we_b1 = (const float*)d_in[13];
    const float* we_w2 = (const float*)d_in[14];
    const float* we_b2 = (const float*)d_in[15];
    const float* wm_w1 = (const float*)d_in[16];
    const float* wm_b1 = (const float*)d_in[17];
    const float* wm_w2 = (const float*)d_in[18];
    const float* wm_b2 = (const float*)d_in[19];

    // ws layout: wbf (8*4096 bf16 = 64KB) | hs (12.8MB bf16) | hd (12.8MB bf16)
    unsigned short* wbf = (unsigned short*)d_ws;
    unsigned short* hs  = wbf + 8 * 4096;
    unsigned short* hd  = hs + (size_t)NNODES * 64;

    convert_w_kernel<<<32, 256, 0, stream>>>(
        ws_w1, ws_w2, wd_w1, wd_w2, we_w1, we_w2, wm_w1, wm_w2, wbf);

    node_mlp_kernel<<<(NNODES + 63) / 64, 256, 0, stream>>>(
        node_feats, wbf, ws_b1, ws_b2, wd_b1, wd_b2, hs, hd);

    hipMemsetAsync(d_out, 0, (size_t)out_size * sizeof(float), stream);

    edge_kernel<<<NEDGES / 64, 256, 0, stream>>>(
        edge_feats, hs, hd, src, dst, wbf, we_b1, we_b2, wm_b1, wm_b2, (float*)d_out);

    finalize_kernel<<<(NNODES * 64) / (256 * 4), 256, 0, stream>>>(
        node_feats, (float*)d_out);
}